// Round 3
// baseline (1554.922 us; speedup 1.0000x reference)
//
#include <hip/hip_runtime.h>

#define DIM 64
#define KC 512
#define BLK 256          // main: 4 waves per block
#define BLKP 256         // prep block size
#define RSB 256          // rescan block size
#define PT 4             // A-tiles (16 points each) per wave -> 64 points/wave
#define NTILE (KC / 16)  // 32 B-tiles of 16 centroids
#define LIST_CAP 500000

// 4-MFMA certificate (unchanged from R2, which passed absmax=0).
// v = Hx.Hc + Hx.Lc/2048; dropped term exactly r_x.c, r_x = x - fl16(x).
// Lx2 = ||r_x||^2 exact per point (Sterbenz). Certified iff
// best - sec > 2.1*sqrt(Lx2*c2max) + 3e-3.
#define THR_A 2.1f
#define THR_B 3.0e-3f

typedef _Float16 half8   __attribute__((ext_vector_type(8)));
typedef float    floatx4 __attribute__((ext_vector_type(4)));

// Prep: centroid (hi, lo*2048) fp16 frags in MFMA B-stream order + exact fp32
// ||c||^2 (R1 op order, rescan + cert) + negated halves (-c2/2, main-loop acc
// init) + zero rescan counter. Runs every launch.
__global__ __launch_bounds__(BLKP) void kmeans_prep(
    const float* __restrict__ c, _Float16* __restrict__ frH,
    _Float16* __restrict__ frL, float* __restrict__ g_sc2,
    float* __restrict__ g_negh, unsigned* __restrict__ rs_count)
{
    const int b = blockIdx.x;
    if (b < 128) {
        const int e  = b * BLKP + threadIdx.x;
        const int cr = e >> 6, d = e & 63;
        const int T  = cr >> 4, ni = cr & 15;
        const int ch = d >> 5, q = (d >> 3) & 3, j = d & 7;
        const int pos = ((T * 2 + ch) * 64 + (q * 16 + ni)) * 8 + j;
        const float f = c[e];
        const _Float16 h = (_Float16)f;
        frH[pos] = h;
        frL[pos] = (_Float16)((f - (float)h) * 2048.0f);
    } else {
        if (b == 128 && threadIdx.x == 0) *rs_count = 0u;
        const int k = (b - 128) * BLKP + threadIdx.x;
        const float* crow = c + (long)k * DIM;
        float s0 = 0.f, s1 = 0.f, s2 = 0.f, s3 = 0.f;
        #pragma unroll
        for (int d = 0; d < DIM; d += 4) {
            s0 = fmaf(crow[d + 0], crow[d + 0], s0);
            s1 = fmaf(crow[d + 1], crow[d + 1], s1);
            s2 = fmaf(crow[d + 2], crow[d + 2], s2);
            s3 = fmaf(crow[d + 3], crow[d + 3], s3);
        }
        const float s = (s0 + s1) + (s2 + s3);
        g_sc2[k]  = s;            // exact, for rescan + c2max
        g_negh[k] = -0.5f * s;    // exact (x0.5), main acc init
    }
}

// Main, V3: NO LDS, NO barriers. B-frags stream global->VGPR from the
// L2-resident 128 KB frag arrays with a manual 1-deep double buffer
// (A/B reg sets, static indexing). R2 post-mortem: the LDS version was
// latency-bound (Occ 20%, all pipes <40%) on per-group barrier drains;
// this removes every barrier and lets the compiler emit counted vmcnt
// waits per reg-load, which it does well. PT=4 halves wave count ->
// B-traffic 2 GB -> 1 GB of L2 reads (~30-40 us floor).
__global__ __launch_bounds__(BLK)
__attribute__((amdgpu_waves_per_eu(2)))
void kmeans_mfma(const float* __restrict__ x,
                 const _Float16* __restrict__ frH, const _Float16* __restrict__ frL,
                 const float* __restrict__ g_sc2, const float* __restrict__ g_negh,
                 int* __restrict__ out, unsigned* __restrict__ rs_count,
                 int* __restrict__ rs_list, int n)
{
    const int tid  = threadIdx.x;
    const int wave = tid >> 6;
    const int lane = tid & 63;
    const int nidx = lane & 15;
    const int quad = lane >> 4;

    const long jobBase = ((long)blockIdx.x * 4 + wave) * (PT * 16);

    const half8* __restrict__ gH = (const half8*)frH;   // 16B-aligned frag stream
    const half8* __restrict__ gL = (const half8*)frL;

    // A fragments (hi) + exact ||x - fl16(x)||^2 per point.
    half8 ah[PT][2];
    float lx2v[PT];
    #pragma unroll
    for (int pt = 0; pt < PT; ++pt) {
        long row = jobBase + pt * 16 + nidx;
        if (row > (long)n - 1) row = (long)n - 1;
        float lx2 = 0.f;
        #pragma unroll
        for (int ch = 0; ch < 2; ++ch) {
            const float* xp = x + row * DIM + ch * 32 + quad * 8;
            float4 v0 = *(const float4*)xp;
            float4 v1 = *(const float4*)(xp + 4);
            float fs[8] = {v0.x, v0.y, v0.z, v0.w, v1.x, v1.y, v1.z, v1.w};
            #pragma unroll
            for (int j = 0; j < 8; ++j) {
                const _Float16 h = (_Float16)fs[j];
                ah[pt][ch][j] = h;
                const float r = fs[j] - (float)h;   // exact (Sterbenz)
                lx2 = fmaf(r, r, lx2);
            }
        }
        lx2 += __shfl_xor(lx2, 16, 64);
        lx2 += __shfl_xor(lx2, 32, 64);
        lx2v[pt] = lx2;   // uniform across quads; indexed by nidx
    }

    // argmax state over v' = dot - c2/2 (argmax v' == argmin d2).
    float best[PT][4], sec[PT][4];
    int   bidx[PT][4];
    #pragma unroll
    for (int pt = 0; pt < PT; ++pt)
        #pragma unroll
        for (int r = 0; r < 4; ++r) {
            best[pt][r] = -3.402823466e38f;
            sec[pt][r]  = -3.402823466e38f;
            bidx[pt][r] = 0;
        }

    // ---- barrier-free streamed main loop, 1-deep pipelined ----
    half8 bh0A, bh1A, bl0A, bl1A, bh0B, bh1B, bl0B, bl1B;
    float negA, negB;

    auto loadT = [&](int T, half8& b0, half8& b1, half8& l0, half8& l1, float& ng) {
        const int off = T * 128 + lane;   // half8 units: 2 KB per tile
        b0 = gH[off];       b1 = gH[off + 64];
        l0 = gL[off];       l1 = gL[off + 64];
        ng = g_negh[T * 16 + nidx];       // 64B window, L1-hot
    };
    auto computeT = [&](int T, const half8& b0, const half8& b1,
                        const half8& l0, const half8& l1, float ng) {
        const int kidx = T * 16 + nidx;
        #pragma unroll
        for (int pt = 0; pt < PT; ++pt) {
            floatx4 am = {ng, ng, ng, ng};
            floatx4 ac = {0.f, 0.f, 0.f, 0.f};
            am = __builtin_amdgcn_mfma_f32_16x16x32_f16(ah[pt][0], b0, am, 0, 0, 0);
            am = __builtin_amdgcn_mfma_f32_16x16x32_f16(ah[pt][1], b1, am, 0, 0, 0);
            ac = __builtin_amdgcn_mfma_f32_16x16x32_f16(ah[pt][0], l0, ac, 0, 0, 0);
            ac = __builtin_amdgcn_mfma_f32_16x16x32_f16(ah[pt][1], l1, ac, 0, 0, 0);
            const floatx4 vv = am + ac * 4.8828125e-4f;    // + Hx.Lc/2048
            #pragma unroll
            for (int r = 0; r < 4; ++r) {
                const bool gt = vv[r] > best[pt][r];       // strict > : first-idx ties
                sec[pt][r]  = __builtin_amdgcn_fmed3f(sec[pt][r], vv[r], best[pt][r]);
                best[pt][r] = fmaxf(best[pt][r], vv[r]);
                bidx[pt][r] = gt ? kidx : bidx[pt][r];
            }
        }
    };

    loadT(0, bh0A, bh1A, bl0A, bl1A, negA);
    #pragma unroll
    for (int t = 0; t < NTILE; t += 2) {
        loadT(t + 1, bh0B, bh1B, bl0B, bl1B, negB);
        computeT(t, bh0A, bh1A, bl0A, bl1A, negA);
        if (t + 2 < NTILE) loadT(t + 2, bh0A, bh1A, bl0A, bl1A, negA);
        computeT(t + 1, bh0B, bh1B, bl0B, bl1B, negB);
    }

    // butterfly over the 16 lanes (n) of each quad — argmax, smaller idx on ties
    #pragma unroll
    for (int off = 1; off < 16; off <<= 1) {
        #pragma unroll
        for (int pt = 0; pt < PT; ++pt)
            #pragma unroll
            for (int r = 0; r < 4; ++r) {
                const float ob = __shfl_xor(best[pt][r], off, 64);
                const int   oi = __shfl_xor(bidx[pt][r], off, 64);
                const float os = __shfl_xor(sec[pt][r],  off, 64);
                const bool take = (ob > best[pt][r]) ||
                                  (ob == best[pt][r] && oi < bidx[pt][r]);
                const float loser = take ? best[pt][r] : ob;
                sec[pt][r]  = fmaxf(fmaxf(sec[pt][r], os), loser);
                best[pt][r] = take ? ob : best[pt][r];
                bidx[pt][r] = take ? oi : bidx[pt][r];
            }
    }

    // c2max for the certificate: 8 L2-hot loads + wave reduce
    float c2m = g_sc2[lane];
    #pragma unroll
    for (int k2 = 64; k2 < KC; k2 += 64) c2m = fmaxf(c2m, g_sc2[lane + k2]);
    #pragma unroll
    for (int off = 1; off < 64; off <<= 1) c2m = fmaxf(c2m, __shfl_xor(c2m, off, 64));

    // write: lane nidx owns (pt_w = nidx>>2, r_w = nidx&3) at row quad*4+r_w
    const int pt_w = nidx >> 2;    // all 16 nidx used (PT=4)
    const int r_w  = nidx & 3;
    float b = 0.f, s = 0.f; int bi = 0;
    #pragma unroll
    for (int pt = 0; pt < PT; ++pt)
        #pragma unroll
        for (int r = 0; r < 4; ++r) {
            const bool m = (pt == pt_w) && (r == r_w);
            b  = m ? best[pt][r] : b;
            s  = m ? sec[pt][r]  : s;
            bi = m ? bidx[pt][r] : bi;
        }
    // route this point's Lx2 to the writer lane (source nidx' = quad*4+r_w)
    const int srcl = quad * 4 + r_w;
    float lxx = __shfl(lx2v[0], srcl, 64);
    #pragma unroll
    for (int pt = 1; pt < PT; ++pt) {
        const float tmp = __shfl(lx2v[pt], srcl, 64);
        lxx = (pt_w == pt) ? tmp : lxx;
    }
    const float thr = fmaf(THR_A, sqrtf(lxx * c2m), THR_B);

    const long p = jobBase + (long)pt_w * 16 + quad * 4 + r_w;

    const bool valid = (p < n);
    if (valid) out[p] = bi;                          // exact when certified
    const bool need  = valid && !(b - s > thr);      // uncertified -> rescan

    // wave-aggregated append: ONE atomic per wave
    const unsigned long long m = __ballot(need);
    if (m) {
        const int leader = (int)(__ffsll((unsigned long long)m) - 1);
        unsigned base = 0;
        if (lane == leader) base = atomicAdd(rs_count, (unsigned)__popcll(m));
        base = __shfl(base, leader, 64);
        if (need) {
            const unsigned idx = base + (unsigned)__popcll(m & ((1ull << lane) - 1ull));
            if (idx < LIST_CAP) rs_list[idx] = (int)p;
        }
    }
}

// Exact rescan, LDS-staged: ct4[d4*513 + k] holds c[k][4d4..4d4+3].
// Stride 513 == 1 (mod 32 banks) -> conflict-free writes AND column reads.
// fma chains bit-identical to R1.
__global__ __launch_bounds__(RSB) void kmeans_rescan(
    const float* __restrict__ x, const float* __restrict__ c,
    const float* __restrict__ g_sc2, const unsigned* __restrict__ rs_count,
    const int* __restrict__ rs_list, int* __restrict__ out)
{
    __shared__ float4 ct4[16 * 513];   // 128.25 KB
    __shared__ float  s_c2[KC];        // 2 KB

    const int tid = threadIdx.x;
    for (int e = tid; e < KC * 16; e += RSB) {          // coalesced row-chunk reads
        const int k = e >> 4, d4 = e & 15;
        ct4[d4 * 513 + k] = *(const float4*)(c + (long)k * DIM + d4 * 4);
    }
    for (int k = tid; k < KC; k += RSB) s_c2[k] = g_sc2[k];
    __syncthreads();

    const int lane  = tid & 63;
    const int gwave = blockIdx.x * (RSB / 64) + (tid >> 6);
    const int nwave = gridDim.x * (RSB / 64);
    unsigned cnt = *rs_count;
    if (cnt > LIST_CAP) cnt = LIST_CAP;

    for (unsigned j = gwave; j < cnt; j += nwave) {
        const int p = rs_list[j];
        const float* xrow = x + (long)p * DIM;          // wave-uniform -> s_load

        float x20 = 0.f, x21 = 0.f, x22 = 0.f, x23 = 0.f;
        #pragma unroll
        for (int d = 0; d < DIM; d += 4) {
            x20 = fmaf(xrow[d + 0], xrow[d + 0], x20);
            x21 = fmaf(xrow[d + 1], xrow[d + 1], x21);
            x22 = fmaf(xrow[d + 2], xrow[d + 2], x22);
            x23 = fmaf(xrow[d + 3], xrow[d + 3], x23);
        }
        const float x2 = (x20 + x21) + (x22 + x23);

        float bb = 3.402823466e38f; int bbi = 0x7fffffff;
        #pragma unroll
        for (int kk = 0; kk < 8; ++kk) {
            const int k = kk * 64 + lane;               // distinct ks; lex reduce handles order
            float d0 = 0.f, d1 = 0.f, d2a = 0.f, d3 = 0.f;
            #pragma unroll
            for (int d4 = 0; d4 < 16; ++d4) {
                const float4 q = ct4[d4 * 513 + k];     // ds_read_b128, conflict-free
                d0  = fmaf(q.x, xrow[4 * d4 + 0], d0);
                d1  = fmaf(q.y, xrow[4 * d4 + 1], d1);
                d2a = fmaf(q.z, xrow[4 * d4 + 2], d2a);
                d3  = fmaf(q.w, xrow[4 * d4 + 3], d3);
            }
            const float dot = (d0 + d1) + (d2a + d3);
            float d2v = (x2 + s_c2[k]) - 2.0f * dot;
            d2v = fmaxf(d2v, 0.0f);
            const bool l2 = (d2v < bb) || (d2v == bb && k < bbi);
            bb  = l2 ? d2v : bb;
            bbi = l2 ? k   : bbi;
        }
        #pragma unroll
        for (int off = 1; off < 64; off <<= 1) {
            const float ob = __shfl_xor(bb, off, 64);
            const int   oi = __shfl_xor(bbi, off, 64);
            const bool take = (ob < bb) || (ob == bb && oi < bbi);
            bb  = take ? ob : bb;
            bbi = take ? oi : bbi;
        }
        if (lane == 0) out[p] = bbi;
    }
}

extern "C" void kernel_launch(void* const* d_in, const int* in_sizes, int n_in,
                              void* d_out, int out_size, void* d_ws, size_t ws_size,
                              hipStream_t stream) {
    const float* x = (const float*)d_in[0];   // [N, 64] fp32
    const float* c = (const float*)d_in[1];   // [512, 64] fp32
    int* out = (int*)d_out;                   // [N] int32 labels
    const int n = in_sizes[0] / DIM;

    _Float16* frH   = (_Float16*)d_ws;                 // 64 KB
    _Float16* frL   = frH + (KC * DIM);                // 64 KB
    float*    gsc2  = (float*)(frL + (KC * DIM));      // 2 KB
    float*    gnegh = gsc2 + KC;                       // 2 KB
    unsigned* cnt   = (unsigned*)(gnegh + KC);         // 16 B slot
    int*      rlist = (int*)(cnt + 4);                 // <= 2 MB

    kmeans_prep<<<130, BLKP, 0, stream>>>(c, frH, frL, gsc2, gnegh, cnt);

    const int jobs   = (n + PT * 16 - 1) / (PT * 16);  // 64 points per wave
    const int blocks = (jobs + 3) / 4;                 // 4 waves per block
    kmeans_mfma<<<blocks, BLK, 0, stream>>>(x, frH, frL, gsc2, gnegh, out, cnt, rlist, n);

    kmeans_rescan<<<256, RSB, 0, stream>>>(x, c, gsc2, cnt, rlist, out);
}

// Round 4
// 292.903 us; speedup vs baseline: 5.3087x; 5.3087x over previous
//
#include <hip/hip_runtime.h>

#define DIM 64
#define KC 512
#define BLK 256          // main: 4 waves per block
#define BLKP 256         // prep block size
#define RSB 256          // rescan block size
#define PT 2             // A-tiles (16 points each) per wave -> 32 points/wave
#define CG 32            // centroids per LDS group (16 groups); ping-pong fits 18 KB
#define NT (CG / 16)     // 2 centroid tiles per group
#define NGRP (KC / CG)   // 16 groups
#define MARGINH 5e-4f    // cert margin on v' scale (6-MFMA error ~3.5e-4; R0-proven)
#define LIST_CAP 500000

typedef _Float16 half8   __attribute__((ext_vector_type(8)));
typedef float    floatx4 __attribute__((ext_vector_type(4)));

__device__ __forceinline__ void async_cp16(_Float16* lds_base, const _Float16* g_lane) {
    __builtin_amdgcn_global_load_lds(
        (const __attribute__((address_space(1))) unsigned int*)(g_lane),
        (__attribute__((address_space(3))) unsigned int*)(lds_base),
        16, 0, 0);
}

// Prep: centroid (hi, lo*2048) fp16 frags in MFMA B-stream order + exact fp32
// ||c||^2 (rescan, R1 op order) + prefolded -c2/2 (main acc init) + zero
// rescan counter. Runs every launch.
__global__ __launch_bounds__(BLKP) void kmeans_prep(
    const float* __restrict__ c, _Float16* __restrict__ frH,
    _Float16* __restrict__ frL, float* __restrict__ g_sc2,
    float* __restrict__ g_negh, unsigned* __restrict__ rs_count)
{
    const int b = blockIdx.x;
    if (b < 128) {
        const int e  = b * BLKP + threadIdx.x;
        const int cr = e >> 6, d = e & 63;
        const int T  = cr >> 4, ni = cr & 15;
        const int ch = d >> 5, q = (d >> 3) & 3, j = d & 7;
        const int pos = ((T * 2 + ch) * 64 + (q * 16 + ni)) * 8 + j;
        const float f = c[e];
        const _Float16 h = (_Float16)f;
        frH[pos] = h;
        frL[pos] = (_Float16)((f - (float)h) * 2048.0f);
    } else {
        if (b == 128 && threadIdx.x == 0) *rs_count = 0u;
        const int k = (b - 128) * BLKP + threadIdx.x;
        const float* crow = c + (long)k * DIM;
        float s0 = 0.f, s1 = 0.f, s2 = 0.f, s3 = 0.f;
        #pragma unroll
        for (int d = 0; d < DIM; d += 4) {
            s0 = fmaf(crow[d + 0], crow[d + 0], s0);
            s1 = fmaf(crow[d + 1], crow[d + 1], s1);
            s2 = fmaf(crow[d + 2], crow[d + 2], s2);
            s3 = fmaf(crow[d + 3], crow[d + 3], s3);
        }
        const float s = (s0 + s1) + (s2 + s3);
        g_sc2[k]  = s;            // exact, for rescan
        g_negh[k] = -0.5f * s;    // exact (x0.5), main acc init
    }
}

// Main, V4 = R0 envelope (18 KB LDS, 2 waves/EU, 6-MFMA exact hi/lo scheme,
// margin 5e-4 proven absmax=0) + three measured-theory fixes:
//  (a) CG=32 ping-pong: stage(g+1) issued BEFORE compute(g) -> pre-barrier
//      vmcnt(0) drain is ~free. SAME 18 KB footprint (R2's 34 KB cost 2x occ).
//  (b) acc inits hoisted into MFMA C-operands (cinit per t, ZERO per kernel),
//      negh prefolded in prep: 28 -> ~21 VALU per (t,pt).
//  (c) wave-aggregated rescan append (one atomic/wave).
// R3 lesson: no PT=4, no reg-streaming B (spill disaster, 1.6 GB scratch).
__global__ __launch_bounds__(BLK)
__attribute__((amdgpu_waves_per_eu(2)))
void kmeans_mfma(const float* __restrict__ x,
                 const _Float16* __restrict__ frH, const _Float16* __restrict__ frL,
                 const float* __restrict__ g_negh, int* __restrict__ out,
                 unsigned* __restrict__ rs_count, int* __restrict__ rs_list, int n)
{
    __shared__ _Float16 shH[2][NT * 2 * 64 * 8];   // 2 x 4 KB ping-pong
    __shared__ _Float16 shL[2][NT * 2 * 64 * 8];   // 2 x 4 KB ping-pong
    __shared__ float    s_negh[KC];                // 2 KB (-c2/2)

    const int tid  = threadIdx.x;
    const int wave = tid >> 6;
    const int lane = tid & 63;
    const int nidx = lane & 15;
    const int quad = lane >> 4;

    const long jobBase = ((long)blockIdx.x * 4 + wave) * (PT * 16);

    // stage: issue 8 KB (4 hi + 4 lo) of group gg into buffer buf (async).
    // 4 KB = 256 16B chunks = 4 waves x 64 lanes: one cp16 per lane per array.
    auto stage = [&](int gg, int buf) {
        const _Float16* srcH = frH + (long)gg * (NT * 2 * 64 * 8);
        const _Float16* srcL = frL + (long)gg * (NT * 2 * 64 * 8);
        const int chunk = wave * 64;              // wave-uniform base
        async_cp16(&shH[buf][(long)chunk * 8], srcH + (long)(chunk + lane) * 8);
        async_cp16(&shL[buf][(long)chunk * 8], srcL + (long)(chunk + lane) * 8);
    };

    // kick group-0 staging + negh copy; A-frag construction overlaps the latency
    stage(0, 0);
    for (int k2 = tid; k2 < KC; k2 += BLK) s_negh[k2] = g_negh[k2];

    // A fragments (hi + lo*2048), R0-validated construction.
    half8 ah[PT][2], al[PT][2];
    #pragma unroll
    for (int pt = 0; pt < PT; ++pt) {
        long row = jobBase + pt * 16 + nidx;
        if (row > (long)n - 1) row = (long)n - 1;
        #pragma unroll
        for (int ch = 0; ch < 2; ++ch) {
            const float* xp = x + row * DIM + ch * 32 + quad * 8;
            float4 v0 = *(const float4*)xp;
            float4 v1 = *(const float4*)(xp + 4);
            float fs[8] = {v0.x, v0.y, v0.z, v0.w, v1.x, v1.y, v1.z, v1.w};
            #pragma unroll
            for (int j = 0; j < 8; ++j) {
                _Float16 h = (_Float16)fs[j];
                ah[pt][ch][j] = h;
                al[pt][ch][j] = (_Float16)((fs[j] - (float)h) * 2048.0f);
            }
        }
    }

    // argmax state over v' = dot - c2/2 (argmax v' == argmin d2).
    float best[PT][4], sec[PT][4];
    int   bidx[PT][4];
    #pragma unroll
    for (int pt = 0; pt < PT; ++pt)
        #pragma unroll
        for (int r = 0; r < 4; ++r) {
            best[pt][r] = -3.402823466e38f;
            sec[pt][r]  = -3.402823466e38f;
            bidx[pt][r] = 0;
        }

    const floatx4 ZERO = {0.f, 0.f, 0.f, 0.f};   // hoisted ac init

    __syncthreads();   // group-0 data (vmcnt(0) implied) + s_negh ready

    for (int g = 0; g < NGRP; ++g) {
        const int cur = g & 1;
        // issue next group's loads now; they land during this group's compute.
        if (g + 1 < NGRP) stage(g + 1, cur ^ 1);

        #pragma unroll
        for (int t = 0; t < NT; ++t) {
            const half8 bh0 = *(const half8*)&shH[cur][((t * 2 + 0) * 64 + lane) * 8];
            const half8 bh1 = *(const half8*)&shH[cur][((t * 2 + 1) * 64 + lane) * 8];
            const half8 bl0 = *(const half8*)&shL[cur][((t * 2 + 0) * 64 + lane) * 8];
            const half8 bl1 = *(const half8*)&shL[cur][((t * 2 + 1) * 64 + lane) * 8];
            const int   kidx  = g * CG + t * 16 + nidx;
            const float ng    = s_negh[kidx];               // prefolded -c2/2
            const floatx4 cinit = {ng, ng, ng, ng};         // once per t, not per pt
            #pragma unroll
            for (int pt = 0; pt < PT; ++pt) {
                floatx4 am, ac;
                am = __builtin_amdgcn_mfma_f32_16x16x32_f16(ah[pt][0], bh0, cinit, 0, 0, 0);
                am = __builtin_amdgcn_mfma_f32_16x16x32_f16(ah[pt][1], bh1, am, 0, 0, 0);
                ac = __builtin_amdgcn_mfma_f32_16x16x32_f16(ah[pt][0], bl0, ZERO, 0, 0, 0);
                ac = __builtin_amdgcn_mfma_f32_16x16x32_f16(ah[pt][1], bl1, ac, 0, 0, 0);
                ac = __builtin_amdgcn_mfma_f32_16x16x32_f16(al[pt][0], bh0, ac, 0, 0, 0);
                ac = __builtin_amdgcn_mfma_f32_16x16x32_f16(al[pt][1], bh1, ac, 0, 0, 0);
                const floatx4 vv = am + ac * 4.8828125e-4f;    // v' (R0 op order)
                #pragma unroll
                for (int r = 0; r < 4; ++r) {
                    const bool gt = vv[r] > best[pt][r];       // strict > : first-idx ties
                    // exact identity: med3(sec, vv, best_old) == max(sec, min(vv, best_old))
                    sec[pt][r]  = __builtin_amdgcn_fmed3f(sec[pt][r], vv[r], best[pt][r]);
                    best[pt][r] = fmaxf(best[pt][r], vv[r]);
                    bidx[pt][r] = gt ? kidx : bidx[pt][r];
                }
            }
        }
        // barrier drains vmcnt(0): stage(g+1) had the whole compute to land
        if (g + 1 < NGRP) __syncthreads();
    }

    // butterfly over the 16 lanes (n) of each quad — argmax, smaller idx on ties
    #pragma unroll
    for (int off = 1; off < 16; off <<= 1) {
        #pragma unroll
        for (int pt = 0; pt < PT; ++pt)
            #pragma unroll
            for (int r = 0; r < 4; ++r) {
                const float ob = __shfl_xor(best[pt][r], off, 64);
                const int   oi = __shfl_xor(bidx[pt][r], off, 64);
                const float os = __shfl_xor(sec[pt][r],  off, 64);
                const bool take = (ob > best[pt][r]) ||
                                  (ob == best[pt][r] && oi < bidx[pt][r]);
                const float loser = take ? best[pt][r] : ob;
                sec[pt][r]  = fmaxf(fmaxf(sec[pt][r], os), loser);
                best[pt][r] = take ? ob : best[pt][r];
                bidx[pt][r] = take ? oi : bidx[pt][r];
            }
    }

    // write: lanes nidx 0..7 own (pt_w = nidx>>2, r_w = nidx&3) at row quad*4+r_w
    const int pt_w = nidx >> 2;    // 0..1 used; nidx >= 8 idle
    const int r_w  = nidx & 3;
    float b = 0.f, s = 0.f; int bi = 0;
    #pragma unroll
    for (int pt = 0; pt < PT; ++pt)
        #pragma unroll
        for (int r = 0; r < 4; ++r) {
            const bool m = (pt == pt_w) && (r == r_w);
            b  = m ? best[pt][r] : b;
            s  = m ? sec[pt][r]  : s;
            bi = m ? bidx[pt][r] : bi;
        }
    const long p = jobBase + (long)pt_w * 16 + quad * 4 + r_w;

    const bool valid = (nidx < 8) && (p < n);
    if (valid) out[p] = bi;                          // exact when certified
    const bool need  = valid && !(b - s > MARGINH);  // uncertified -> rescan

    // wave-aggregated append: ONE atomic per wave
    const unsigned long long m = __ballot(need);
    if (m) {
        const int leader = (int)(__ffsll((unsigned long long)m) - 1);
        unsigned base = 0;
        if (lane == leader) base = atomicAdd(rs_count, (unsigned)__popcll(m));
        base = __shfl(base, leader, 64);
        if (need) {
            const unsigned idx = base + (unsigned)__popcll(m & ((1ull << lane) - 1ull));
            if (idx < LIST_CAP) rs_list[idx] = (int)p;
        }
    }
}

// Exact rescan, LDS-staged: ct4[d4*513 + k] holds c[k][4d4..4d4+3].
// Stride 513 == 1 (mod 32 banks) -> conflict-free writes AND column reads.
// fma chains bit-identical to R1. Blocks with no work exit before staging.
__global__ __launch_bounds__(RSB) void kmeans_rescan(
    const float* __restrict__ x, const float* __restrict__ c,
    const float* __restrict__ g_sc2, const unsigned* __restrict__ rs_count,
    const int* __restrict__ rs_list, int* __restrict__ out)
{
    __shared__ float4 ct4[16 * 513];   // 128.25 KB
    __shared__ float  s_c2[KC];        // 2 KB

    unsigned cnt = *rs_count;
    if (cnt > LIST_CAP) cnt = LIST_CAP;
    if ((unsigned)(blockIdx.x * (RSB / 64)) >= cnt) return;   // no work: skip staging

    const int tid = threadIdx.x;
    for (int e = tid; e < KC * 16; e += RSB) {          // coalesced row-chunk reads
        const int k = e >> 4, d4 = e & 15;
        ct4[d4 * 513 + k] = *(const float4*)(c + (long)k * DIM + d4 * 4);
    }
    for (int k = tid; k < KC; k += RSB) s_c2[k] = g_sc2[k];
    __syncthreads();

    const int lane  = tid & 63;
    const int gwave = blockIdx.x * (RSB / 64) + (tid >> 6);
    const int nwave = gridDim.x * (RSB / 64);

    for (unsigned j = gwave; j < cnt; j += nwave) {
        const int p = rs_list[j];
        const float* xrow = x + (long)p * DIM;          // wave-uniform -> s_load

        float x20 = 0.f, x21 = 0.f, x22 = 0.f, x23 = 0.f;
        #pragma unroll
        for (int d = 0; d < DIM; d += 4) {
            x20 = fmaf(xrow[d + 0], xrow[d + 0], x20);
            x21 = fmaf(xrow[d + 1], xrow[d + 1], x21);
            x22 = fmaf(xrow[d + 2], xrow[d + 2], x22);
            x23 = fmaf(xrow[d + 3], xrow[d + 3], x23);
        }
        const float x2 = (x20 + x21) + (x22 + x23);

        float bb = 3.402823466e38f; int bbi = 0x7fffffff;
        #pragma unroll
        for (int kk = 0; kk < 8; ++kk) {
            const int k = kk * 64 + lane;               // distinct ks; lex reduce handles order
            float d0 = 0.f, d1 = 0.f, d2a = 0.f, d3 = 0.f;
            #pragma unroll
            for (int d4 = 0; d4 < 16; ++d4) {
                const float4 q = ct4[d4 * 513 + k];     // ds_read_b128, conflict-free
                d0  = fmaf(q.x, xrow[4 * d4 + 0], d0);
                d1  = fmaf(q.y, xrow[4 * d4 + 1], d1);
                d2a = fmaf(q.z, xrow[4 * d4 + 2], d2a);
                d3  = fmaf(q.w, xrow[4 * d4 + 3], d3);
            }
            const float dot = (d0 + d1) + (d2a + d3);
            float d2v = (x2 + s_c2[k]) - 2.0f * dot;
            d2v = fmaxf(d2v, 0.0f);
            const bool l2 = (d2v < bb) || (d2v == bb && k < bbi);
            bb  = l2 ? d2v : bb;
            bbi = l2 ? k   : bbi;
        }
        #pragma unroll
        for (int off = 1; off < 64; off <<= 1) {
            const float ob = __shfl_xor(bb, off, 64);
            const int   oi = __shfl_xor(bbi, off, 64);
            const bool take = (ob < bb) || (ob == bb && oi < bbi);
            bb  = take ? ob : bb;
            bbi = take ? oi : bbi;
        }
        if (lane == 0) out[p] = bbi;
    }
}

extern "C" void kernel_launch(void* const* d_in, const int* in_sizes, int n_in,
                              void* d_out, int out_size, void* d_ws, size_t ws_size,
                              hipStream_t stream) {
    const float* x = (const float*)d_in[0];   // [N, 64] fp32
    const float* c = (const float*)d_in[1];   // [512, 64] fp32
    int* out = (int*)d_out;                   // [N] int32 labels
    const int n = in_sizes[0] / DIM;

    _Float16* frH   = (_Float16*)d_ws;                 // 64 KB
    _Float16* frL   = frH + (KC * DIM);                // 64 KB
    float*    gsc2  = (float*)(frL + (KC * DIM));      // 2 KB
    float*    gnegh = gsc2 + KC;                       // 2 KB
    unsigned* cnt   = (unsigned*)(gnegh + KC);         // 16 B slot
    int*      rlist = (int*)(cnt + 4);                 // <= 2 MB

    kmeans_prep<<<130, BLKP, 0, stream>>>(c, frH, frL, gsc2, gnegh, cnt);

    const int jobs   = (n + PT * 16 - 1) / (PT * 16);  // 32 points per wave
    const int blocks = (jobs + 3) / 4;                 // 4 waves per block
    kmeans_mfma<<<blocks, BLK, 0, stream>>>(x, frH, frL, gnegh, out, cnt, rlist, n);

    kmeans_rescan<<<256, RSB, 0, stream>>>(x, c, gsc2, cnt, rlist, out);
}